// Round 11
// baseline (252.890 us; speedup 1.0000x reference)
//
#include <hip/hip_runtime.h>
#include <hip/hip_bf16.h>
#include <math.h>

#define SS 8
#define NN 32
#define DD 64
#define NP 496    // 32*31/2
#define LDAH 72   // padded row stride (f16 elems) for sAiH/sBjH; 144B, 16B-aligned

typedef short v8s __attribute__((ext_vector_type(8)));      // 8 bf16 (4 VGPRs)
typedef float v4f __attribute__((ext_vector_type(4)));      // MFMA C/D frag
typedef float f2  __attribute__((ext_vector_type(2)));      // packed fp32 pair
typedef _Float16 h8v __attribute__((ext_vector_type(8)));   // 8 f16 (4 VGPRs)

union FragU { uint4 u; v8s s; };
union Q2    { float4 q; f2 h[2]; };

static __device__ __forceinline__ f2 f2m(float a, float b) { f2 r; r.x = a; r.y = b; return r; }
static __device__ __forceinline__ f2 splat2(float s) { f2 r; r.x = s; r.y = s; return r; }
static __device__ __forceinline__ f2 pk_fma(f2 a, f2 b, f2 c) {
#if __has_builtin(__builtin_elementwise_fma)
    return __builtin_elementwise_fma(a, b, c);
#else
    return f2m(fmaf(a.x, b.x, c.x), fmaf(a.y, b.y, c.y));
#endif
}
static __device__ __forceinline__ h8v splat8h(float s) {
    const _Float16 h = (_Float16)s;
    h8v r = {h, h, h, h, h, h, h, h};
    return r;
}
static __device__ __forceinline__ h8v splat8hh(_Float16 h) {
    h8v r = {h, h, h, h, h, h, h, h};
    return r;
}

__device__ __forceinline__ float wrap_pi(float d) {
    return fmaf(-6.28318530717958647692f, rintf(d * 0.15915494309189533577f), d);
}
__device__ __forceinline__ float sigmoid_(float x) {
    return __builtin_amdgcn_rcpf(1.0f + __expf(-x));
}
// f32 packed GELU (epilogue only). A&S rational, |eps|<=5e-4.
__device__ __forceinline__ f2 gelu2(f2 x) {
#if __has_builtin(__builtin_elementwise_max)
    f2 ax = __builtin_elementwise_max(x, -x);
#else
    f2 ax = f2m(fabsf(x.x), fabsf(x.y));
#endif
    f2 az = ax * splat2(0.70710678118654752440f);
    f2 d = pk_fma(splat2(0.078108f), az, splat2(0.000972f));
    d = pk_fma(d, az, splat2(0.230389f));
    d = pk_fma(d, az, splat2(0.278393f));
    d = pk_fma(d, az, splat2(1.0f));
    f2 t = f2m(__builtin_amdgcn_rcpf(d.x), __builtin_amdgcn_rcpf(d.y));
    f2 t2 = t * t;
    f2 a = ax * splat2(0.5f);
    f2 base = pk_fma(x, splat2(0.5f), a);
    f2 u = a * t2;
    return pk_fma(-u, t2, base);
}
// Packed-f16 GELU (kept from R10: equal speed to f32 per the R10 null, but
// operates on the f16 h1 directly -> no unpack; inf-flow safe).
__device__ __forceinline__ h8v gelu8h(h8v x) {
    h8v ax = __builtin_elementwise_max(x, -x);
    h8v az = ax * splat8h(0.70710678118654752440f);
    h8v d = __builtin_elementwise_fma(splat8h(0.078108f), az, splat8h(0.000972f));
    d = __builtin_elementwise_fma(d, az, splat8h(0.230389f));
    d = __builtin_elementwise_fma(d, az, splat8h(0.278393f));
    d = __builtin_elementwise_fma(d, az, splat8h(1.0f));
    h8v t;
    #pragma unroll
    for (int k = 0; k < 8; ++k)
#if __has_builtin(__builtin_amdgcn_rcph)
        t[k] = __builtin_amdgcn_rcph(d[k]);
#else
        t[k] = (_Float16)__builtin_amdgcn_rcpf((float)d[k]);
#endif
    h8v t2 = t * t;
    h8v a = ax * splat8h(0.5f);
    h8v base = __builtin_elementwise_fma(x, splat8h(0.5f), a);
    h8v u = a * t2;
    return __builtin_elementwise_fma(-u, t2, base);
}
__device__ __forceinline__ unsigned int pack_bf16_rne(float x0, float x1) {
    union { __hip_bfloat162 h2; unsigned int u; } cv;
    float2 f; f.x = x0; f.y = x1;
    cv.h2 = __float22bfloat162_rn(f);
    return cv.u;
}
// residual-lo pack: bf16(x - f32(bf16_hi(x))) for a packed hi word.
__device__ __forceinline__ unsigned int res_pack(unsigned int hw, float x0, float x1) {
    const float f0 = __uint_as_float(hw << 16);
    const float f1 = __uint_as_float(hw & 0xFFFF0000u);
    return pack_bf16_rne(x0 - f0, x1 - f1);
}
// 16-lane DPP row-rotation butterfly sum (every lane ends with the row sum).
__device__ __forceinline__ float row_reduce16(float x) {
    int v;
    v = __builtin_amdgcn_update_dpp(0, __float_as_int(x), 0x128, 0xf, 0xf, false);
    x += __int_as_float(v);
    v = __builtin_amdgcn_update_dpp(0, __float_as_int(x), 0x124, 0xf, 0xf, false);
    x += __int_as_float(v);
    v = __builtin_amdgcn_update_dpp(0, __float_as_int(x), 0x122, 0xf, 0xf, false);
    x += __int_as_float(v);
    v = __builtin_amdgcn_update_dpp(0, __float_as_int(x), 0x121, 0xf, 0xf, false);
    x += __int_as_float(v);
    return x;
}
// W2 B-fragment in f16.
__device__ __forceinline__ h8v build_w2_fragh(const float* __restrict__ W2,
                                              int kb, int col) {
    h8v r;
    #pragma unroll
    for (int k = 0; k < 8; ++k) r[k] = (_Float16)W2[(kb + k) * 32 + col];
    return r;
}

// History: R0-R8 exhausted static resources (LDS 38-42KB, VGPR 64-104): dur
// pinned ~89.5us; occupancy tracks VGPR-permitted waves but never exceeds
// ~2.2 blocks resident. R9 (phase A -> MFMA): -7%. R10 (f16 main loop): FLAT
// -> VOP3P pipe is FLOP-rate-equal f16/f32 on CDNA4; dtype is not a lever.
// Ledger: ~47us/SIMD VALU-issue + ~36us all-waves-stalled. In-wave ILP
// (R5/R7) and 8-wave blocks (R4) both failed. THIS round: split each batch
// across 2 blocks (grid 4096). Per block: same prologue + phase A (dup,
// ~+7% work), but only 16 of 31 m-tiles (4 rounds) and half the scal phase.
// sAdj/barrier3/writeback deleted: epilogue stores its 2 cells straight to
// global (byte-disjoint across blocks; ho=0 writes diag zeros). Independent
// instruction streams per SIMD double at zero VGPR cost.
__global__ __launch_bounds__(256, 2) void edge_kernel(
    const float* __restrict__ cel,    // (B,S,N,D)
    const float* __restrict__ theta,  // (B,N)
    const float* __restrict__ phi,
    const float* __restrict__ vel,
    const float* __restrict__ rad,
    const float* __restrict__ lon,
    const float* __restrict__ W1,     // (134,64)
    const float* __restrict__ b1,     // (64)
    const float* __restrict__ W2,     // (64,32)
    const float* __restrict__ b2,     // (32)
    const float* __restrict__ W3,     // (32)
    const float* __restrict__ b3,     // (1)
    const float* __restrict__ pw,     // (6)
    float* __restrict__ out)          // (B,N,N)
{
    __shared__ __align__(16) _Float16 sAiH[NN * LDAH];  // fi@W1[0:64]+b1, f16
    __shared__ __align__(16) _Float16 sBjH[NN * LDAH];  // fj@W1[64:128], f16
    __shared__ __align__(16) float sScal[NP * 8];       // {td,pd,vd,rr}|{ld,pr,gate,-}
    __shared__ unsigned char sI[NP], sJ[NP];

    const int bx = blockIdx.x;
    const int b  = bx >> 1;           // batch
    const int ho = bx & 1;            // tile-half owner: 0 -> tiles 0..15, 1 -> 16..30
    const int t = threadIdx.x;
    const int ml = t & 15;            // frag row-within-tile / C col
    const int ql = (t >> 4) & 3;      // frag k-quad / C row-quad
    const int wv = t >> 6;            // wave id
    const int kA = ql * 8;            // this lane's ks0 k-base

    float* __restrict__ ob = out + (size_t)b * 1024;
    // diagonal zeros (out is re-poisoned between runs; pairs cover off-diag only)
    if (ho == 0 && t < 32) ob[t * 33] = 0.0f;

    // ---- W2 B-fragments (f16) straight from global ----
    h8v f00h = build_w2_fragh(W2, 0 * 32 + kA, 0 * 16 + ml);
    h8v f01h = build_w2_fragh(W2, 1 * 32 + kA, 0 * 16 + ml);
    h8v f10h = build_w2_fragh(W2, 0 * 32 + kA, 1 * 16 + ml);
    h8v f11h = build_w2_fragh(W2, 1 * 32 + kA, 1 * 16 + ml);
    const float b2v0 = b2[ml], b2v1 = b2[16 + ml];
    const float w3v0 = W3[ml], w3v1 = W3[16 + ml];
    const float b3s  = b3[0];

    // ---- staging: full triu pair table (gather needs all of it) ----
    if (t < 31) {
        int off = t * 31 - (t * (t - 1)) / 2;
        for (int j = t + 1; j < 32; ++j) {
            sI[off] = (unsigned char)t;
            sJ[off] = (unsigned char)j;
            ++off;
        }
    }
    __syncthreads();   // barrier 1

    // ---- per-pair scalars + gate, OWNED HALF ONLY (p in [ho*256, ho*256+256)
    //      intersect [0,496)): one strided pass, block1 lanes t>=240 idle ----
    {
        const int p = ho * 256 + t;
        if (p < NP) {
            const int i = sI[p], j = sJ[p];
            const float td = wrap_pi(theta[b * NN + i] - theta[b * NN + j]);
            const float pd = wrap_pi(phi[b * NN + i] - phi[b * NN + j]);
            const float vd = vel[b * NN + i] - vel[b * NN + j];
            const float rr = rad[b * NN + i] * __builtin_amdgcn_rcpf(rad[b * NN + j] + 1e-8f);
            const float ld = wrap_pi(lon[b * NN + i] - lon[b * NN + j]);
            const float pr = __cosf(td) * __cosf(pd);
            const float pf = fabsf(td) * pw[0] + fabsf(pd) * pw[1]
                           + fabsf(vd) * pw[2] + fabsf(rr - 1.0f) * pw[3]
                           + fabsf(ld) * pw[4] + fabsf(pr) * pw[5];
            const int sw = (p >> 2) & 1;   // chunk XOR-swizzle bit
            float4* c0 = (float4*)&sScal[p * 8 + (sw << 2)];
            float4* c1 = (float4*)&sScal[p * 8 + ((sw ^ 1) << 2)];
            *c0 = float4{td, pd, vd, rr};
            *c1 = float4{ld, pr, sigmoid_(pf), 0.0f};
        }
    }

    // ---- phase A on the MATRIX pipe (R9 math, duplicated per half-block):
    //      split-bf16 A x bf16 W1, b1 in C-init; f16 store to LDS ----
    {
        const int w4 = __builtin_amdgcn_readfirstlane(t >> 6);
        const int tg = w4 >> 1;
        const int mt = w4 & 1;
        const float* fbase = cel + ((size_t)b * SS + (SS - 1)) * (NN * DD);
        const float* Arow = fbase + (mt * 16 + ml) * 64;
        const float4 e0 = *(const float4*)(Arow + kA);
        const float4 e1 = *(const float4*)(Arow + kA + 4);
        const float4 e2 = *(const float4*)(Arow + 32 + kA);
        const float4 e3 = *(const float4*)(Arow + 36 + kA);
        FragU Ah0, Al0, Ah1, Al1;
        Ah0.u.x = pack_bf16_rne(e0.x, e0.y);
        Ah0.u.y = pack_bf16_rne(e0.z, e0.w);
        Ah0.u.z = pack_bf16_rne(e1.x, e1.y);
        Ah0.u.w = pack_bf16_rne(e1.z, e1.w);
        Al0.u.x = res_pack(Ah0.u.x, e0.x, e0.y);
        Al0.u.y = res_pack(Ah0.u.y, e0.z, e0.w);
        Al0.u.z = res_pack(Ah0.u.z, e1.x, e1.y);
        Al0.u.w = res_pack(Ah0.u.w, e1.z, e1.w);
        Ah1.u.x = pack_bf16_rne(e2.x, e2.y);
        Ah1.u.y = pack_bf16_rne(e2.z, e2.w);
        Ah1.u.z = pack_bf16_rne(e3.x, e3.y);
        Ah1.u.w = pack_bf16_rne(e3.z, e3.w);
        Al1.u.x = res_pack(Ah1.u.x, e2.x, e2.y);
        Al1.u.y = res_pack(Ah1.u.y, e2.z, e2.w);
        Al1.u.z = res_pack(Ah1.u.z, e3.x, e3.y);
        Al1.u.w = res_pack(Ah1.u.w, e3.z, e3.w);

        const float* WB = W1 + (tg * 64) * 64;
        _Float16* dstS = tg ? sBjH : sAiH;
        #pragma clang loop unroll(disable)   // serial nt: cap VGPR liveness
        for (int nt = 0; nt < 4; ++nt) {
            const int colb = nt * 16 + ml;
            const float* B0p = WB + kA * 64 + colb;
            const float* B1p = WB + (32 + kA) * 64 + colb;
            FragU B0, B1;
            B0.u.x = pack_bf16_rne(B0p[0],   B0p[64]);
            B0.u.y = pack_bf16_rne(B0p[128], B0p[192]);
            B0.u.z = pack_bf16_rne(B0p[256], B0p[320]);
            B0.u.w = pack_bf16_rne(B0p[384], B0p[448]);
            B1.u.x = pack_bf16_rne(B1p[0],   B1p[64]);
            B1.u.y = pack_bf16_rne(B1p[128], B1p[192]);
            B1.u.z = pack_bf16_rne(B1p[256], B1p[320]);
            B1.u.w = pack_bf16_rne(B1p[384], B1p[448]);
            const float cinit = tg ? 0.0f : b1[colb];
            v4f acc = {cinit, cinit, cinit, cinit};
            acc = __builtin_amdgcn_mfma_f32_16x16x32_bf16(Ah0.s, B0.s, acc, 0, 0, 0);
            acc = __builtin_amdgcn_mfma_f32_16x16x32_bf16(Al0.s, B0.s, acc, 0, 0, 0);
            acc = __builtin_amdgcn_mfma_f32_16x16x32_bf16(Ah1.s, B1.s, acc, 0, 0, 0);
            acc = __builtin_amdgcn_mfma_f32_16x16x32_bf16(Al1.s, B1.s, acc, 0, 0, 0);
            dstS[(mt * 16 + ql * 4 + 0) * LDAH + colb] = (_Float16)acc[0];
            dstS[(mt * 16 + ql * 4 + 1) * LDAH + colb] = (_Float16)acc[1];
            dstS[(mt * 16 + ql * 4 + 2) * LDAH + colb] = (_Float16)acc[2];
            dstS[(mt * 16 + ql * 4 + 3) * LDAH + colb] = (_Float16)acc[3];
        }
    }
    __syncthreads();   // barrier 2

    // ---- hoist W1s rows 128..133 for this lane, f16 (48 VGPR) ----
    const float* W1s = W1 + 128 * 64;
    h8v w1fh[6][2];
    #pragma unroll
    for (int s = 0; s < 6; ++s) {
        const float4 u0 = *(const float4*)&W1s[s * 64 + kA];
        const float4 u1 = *(const float4*)&W1s[s * 64 + kA + 4];
        const float4 u2 = *(const float4*)&W1s[s * 64 + 32 + kA];
        const float4 u3 = *(const float4*)&W1s[s * 64 + 36 + kA];
        w1fh[s][0] = h8v{(_Float16)u0.x, (_Float16)u0.y, (_Float16)u0.z, (_Float16)u0.w,
                         (_Float16)u1.x, (_Float16)u1.y, (_Float16)u1.z, (_Float16)u1.w};
        w1fh[s][1] = h8v{(_Float16)u2.x, (_Float16)u2.y, (_Float16)u2.z, (_Float16)u2.w,
                         (_Float16)u3.x, (_Float16)u3.y, (_Float16)u3.z, (_Float16)u3.w};
    }

    // ---- main loop: 4 rounds, owned tiles mtl = ho*16 + r*4 + wv ----
    #pragma clang loop unroll(disable)
    for (int r = 0; r < 4; ++r) {
        const int mtl = ho * 16 + r * 4 + wv;
        if (mtl >= 31) break;                    // wave-uniform (ho=1,r=3,wv=3)
        const int p = mtl * 16 + ml;
        const int i = sI[p], j = sJ[p];
        const int sw = (p >> 2) & 1;
        Q2 S0, S1;
        S0.q = *(const float4*)&sScal[p * 8 + (sw << 2)];        // td,pd,vd,rr
        S1.q = *(const float4*)&sScal[p * 8 + ((sw ^ 1) << 2)];  // ld,pr,gate,-
        const _Float16 sch[6] = {
            (_Float16)S0.q.x, (_Float16)S0.q.y, (_Float16)S0.q.z,
            (_Float16)fminf(S0.q.w, 30000.0f),   // f16-inf guard on rr
            (_Float16)S1.q.x, (_Float16)S1.q.y};
        const _Float16* ArH = &sAiH[i * LDAH];
        const _Float16* BrH = &sBjH[j * LDAH];

        // ks0 half: cols kA..kA+7
        h8v v0;
        {
            const h8v P = *(const h8v*)(ArH + kA);
            const h8v Q = *(const h8v*)(BrH + kA);
            h8v v = P + Q;
            #pragma unroll
            for (int s = 0; s < 6; ++s)
                v = __builtin_elementwise_fma(splat8hh(sch[s]), w1fh[s][0], v);
            v0 = gelu8h(v);
        }
        // ks1 half: cols 32+kA..+7
        h8v v1;
        {
            const h8v P = *(const h8v*)(ArH + 32 + kA);
            const h8v Q = *(const h8v*)(BrH + 32 + kA);
            h8v y = P + Q;
            #pragma unroll
            for (int s = 0; s < 6; ++s)
                y = __builtin_elementwise_fma(splat8hh(sch[s]), w1fh[s][1], y);
            v1 = gelu8h(y);
        }

        // h2 = h1 @ W2 on the matrix pipe (f16 operands)
        v4f acc0 = {b2v0, b2v0, b2v0, b2v0};
        v4f acc1 = {b2v1, b2v1, b2v1, b2v1};
        acc0 = __builtin_amdgcn_mfma_f32_16x16x32_f16(v0, f00h, acc0, 0, 0, 0);
        acc0 = __builtin_amdgcn_mfma_f32_16x16x32_f16(v1, f01h, acc0, 0, 0, 0);
        acc1 = __builtin_amdgcn_mfma_f32_16x16x32_f16(v0, f10h, acc1, 0, 0, 0);
        acc1 = __builtin_amdgcn_mfma_f32_16x16x32_f16(v1, f11h, acc1, 0, 0, 0);

        // epilogue: f32 gelu + W3 dot + DPP reduce; 16 lanes store 2 cells
        // each STRAIGHT TO GLOBAL (blocks write byte-disjoint cells).
        float cres[4];
        #pragma unroll
        for (int rr2 = 0; rr2 < 4; ++rr2) {
            const f2 g = gelu2(f2m(acc0[rr2], acc1[rr2]));
            cres[rr2] = row_reduce16(fmaf(g.y, w3v1, g.x * w3v0));
        }
        const int rsel = ml & 3;
        const float cs = (rsel & 2) ? ((rsel & 1) ? cres[3] : cres[2])
                                    : ((rsel & 1) ? cres[1] : cres[0]);
        const int pe = mtl * 16 + ql * 4 + rsel;
        const int swe = (pe >> 2) & 1;
        const float gate = sScal[pe * 8 + ((swe ^ 1) << 2) + 2];
        const float fe = sigmoid_(cs + b3s) * gate;
        if (ml < 4) {
            const int pi = sI[pe], pj = sJ[pe];
            ob[pi * 32 + pj] = fe;
            ob[pj * 32 + pi] = fe;
        }
    }
}

extern "C" void kernel_launch(void* const* d_in, const int* in_sizes, int n_in,
                              void* d_out, int out_size, void* d_ws, size_t ws_size,
                              hipStream_t stream) {
    const float* cel   = (const float*)d_in[0];
    const float* theta = (const float*)d_in[1];
    const float* phi   = (const float*)d_in[2];
    const float* vel   = (const float*)d_in[3];
    const float* rad   = (const float*)d_in[4];
    const float* lon   = (const float*)d_in[5];
    const float* W1    = (const float*)d_in[6];
    const float* b1    = (const float*)d_in[7];
    const float* W2    = (const float*)d_in[8];
    const float* b2    = (const float*)d_in[9];
    const float* W3    = (const float*)d_in[10];
    const float* b3    = (const float*)d_in[11];
    const float* pw    = (const float*)d_in[12];
    float* out = (float*)d_out;

    const int B = in_sizes[1] / NN;  // theta is (B,N)
    edge_kernel<<<B * 2, 256, 0, stream>>>(cel, theta, phi, vel, rad, lon,
                                           W1, b1, W2, b2, W3, b3, pw, out);
}

// Round 12
// 234.380 us; speedup vs baseline: 1.0790x; 1.0790x over previous
//
#include <hip/hip_runtime.h>
#include <hip/hip_bf16.h>
#include <math.h>

#define SS 8
#define NN 32
#define DD 64
#define NP 496    // 32*31/2
#define LDAH 72   // padded row stride (f16 elems) for sAiH/sBjH; 144B, 16B-aligned

// d_ws layout (bytes): pre-packed weight fragments, written by prep_kernel
// once per launch, read by every edge block. All offsets 16B-aligned.
#define WS_W2  0        // 256 entries x 16B: W2 f16 frags  [frag(4)][ql(4)][ml(16)]
#define WS_W1  4096     // 1024 entries x 16B: W1 bf16 frags [tg(2)][nt(4)][pair(2)][ql(4)][ml(16)]
#define WS_W1S 20480    // 48 entries x 16B: W1 rows128-133 f16 [s(6)][half(2)][ql(4)]
#define WS_TOTAL 21248

typedef short v8s __attribute__((ext_vector_type(8)));      // 8 bf16 (4 VGPRs)
typedef float v4f __attribute__((ext_vector_type(4)));      // MFMA C/D frag
typedef float f2  __attribute__((ext_vector_type(2)));      // packed fp32 pair
typedef _Float16 h8v __attribute__((ext_vector_type(8)));   // 8 f16 (4 VGPRs)

union FragU { uint4 u; v8s s; };
union Q2    { float4 q; f2 h[2]; };

static __device__ __forceinline__ f2 f2m(float a, float b) { f2 r; r.x = a; r.y = b; return r; }
static __device__ __forceinline__ f2 splat2(float s) { f2 r; r.x = s; r.y = s; return r; }
static __device__ __forceinline__ f2 pk_fma(f2 a, f2 b, f2 c) {
#if __has_builtin(__builtin_elementwise_fma)
    return __builtin_elementwise_fma(a, b, c);
#else
    return f2m(fmaf(a.x, b.x, c.x), fmaf(a.y, b.y, c.y));
#endif
}
static __device__ __forceinline__ h8v splat8h(float s) {
    const _Float16 h = (_Float16)s;
    h8v r = {h, h, h, h, h, h, h, h};
    return r;
}
static __device__ __forceinline__ h8v splat8hh(_Float16 h) {
    h8v r = {h, h, h, h, h, h, h, h};
    return r;
}

__device__ __forceinline__ float wrap_pi(float d) {
    return fmaf(-6.28318530717958647692f, rintf(d * 0.15915494309189533577f), d);
}
__device__ __forceinline__ float sigmoid_(float x) {
    return __builtin_amdgcn_rcpf(1.0f + __expf(-x));
}
// f32 packed GELU (epilogue only). A&S rational, |eps|<=5e-4.
__device__ __forceinline__ f2 gelu2(f2 x) {
#if __has_builtin(__builtin_elementwise_max)
    f2 ax = __builtin_elementwise_max(x, -x);
#else
    f2 ax = f2m(fabsf(x.x), fabsf(x.y));
#endif
    f2 az = ax * splat2(0.70710678118654752440f);
    f2 d = pk_fma(splat2(0.078108f), az, splat2(0.000972f));
    d = pk_fma(d, az, splat2(0.230389f));
    d = pk_fma(d, az, splat2(0.278393f));
    d = pk_fma(d, az, splat2(1.0f));
    f2 t = f2m(__builtin_amdgcn_rcpf(d.x), __builtin_amdgcn_rcpf(d.y));
    f2 t2 = t * t;
    f2 a = ax * splat2(0.5f);
    f2 base = pk_fma(x, splat2(0.5f), a);
    f2 u = a * t2;
    return pk_fma(-u, t2, base);
}
// Packed-f16 GELU (R10: rate-equal to f32, but operates on f16 h1 directly).
__device__ __forceinline__ h8v gelu8h(h8v x) {
    h8v ax = __builtin_elementwise_max(x, -x);
    h8v az = ax * splat8h(0.70710678118654752440f);
    h8v d = __builtin_elementwise_fma(splat8h(0.078108f), az, splat8h(0.000972f));
    d = __builtin_elementwise_fma(d, az, splat8h(0.230389f));
    d = __builtin_elementwise_fma(d, az, splat8h(0.278393f));
    d = __builtin_elementwise_fma(d, az, splat8h(1.0f));
    h8v t;
    #pragma unroll
    for (int k = 0; k < 8; ++k)
#if __has_builtin(__builtin_amdgcn_rcph)
        t[k] = __builtin_amdgcn_rcph(d[k]);
#else
        t[k] = (_Float16)__builtin_amdgcn_rcpf((float)d[k]);
#endif
    h8v t2 = t * t;
    h8v a = ax * splat8h(0.5f);
    h8v base = __builtin_elementwise_fma(x, splat8h(0.5f), a);
    h8v u = a * t2;
    return __builtin_elementwise_fma(-u, t2, base);
}
__device__ __forceinline__ unsigned int pack_bf16_rne(float x0, float x1) {
    union { __hip_bfloat162 h2; unsigned int u; } cv;
    float2 f; f.x = x0; f.y = x1;
    cv.h2 = __float22bfloat162_rn(f);
    return cv.u;
}
// residual-lo pack: bf16(x - f32(bf16_hi(x))) for a packed hi word.
__device__ __forceinline__ unsigned int res_pack(unsigned int hw, float x0, float x1) {
    const float f0 = __uint_as_float(hw << 16);
    const float f1 = __uint_as_float(hw & 0xFFFF0000u);
    return pack_bf16_rne(x0 - f0, x1 - f1);
}
// 16-lane DPP row-rotation butterfly sum (every lane ends with the row sum).
__device__ __forceinline__ float row_reduce16(float x) {
    int v;
    v = __builtin_amdgcn_update_dpp(0, __float_as_int(x), 0x128, 0xf, 0xf, false);
    x += __int_as_float(v);
    v = __builtin_amdgcn_update_dpp(0, __float_as_int(x), 0x124, 0xf, 0xf, false);
    x += __int_as_float(v);
    v = __builtin_amdgcn_update_dpp(0, __float_as_int(x), 0x122, 0xf, 0xf, false);
    x += __int_as_float(v);
    v = __builtin_amdgcn_update_dpp(0, __float_as_int(x), 0x121, 0xf, 0xf, false);
    x += __int_as_float(v);
    return x;
}

// Prep kernel: converts W1/W2 to lane-ordered f16/bf16 fragments ONCE per
// launch (R10 and earlier re-did this in all 2048 blocks: ~280 VALU
// instrs/thread of redundant convert+pack, ~11% of the kernel).
__global__ __launch_bounds__(256) void prep_kernel(
    const float* __restrict__ W1, const float* __restrict__ W2,
    unsigned char* __restrict__ ws)
{
    const int idx = blockIdx.x * 256 + threadIdx.x;
    if (idx < 256) {
        // W2 f16 frags: frag {f00,f01,f10,f11}
        const int frag = idx >> 6, ql = (idx >> 4) & 3, ml = idx & 15;
        const int kA = ql * 8;
        const int kb = (frag & 1) ? 32 + kA : kA;
        const int col = (frag >> 1) ? 16 + ml : ml;
        h8v r;
        #pragma unroll
        for (int k = 0; k < 8; ++k) r[k] = (_Float16)W2[(kb + k) * 32 + col];
        *(h8v*)(ws + WS_W2 + idx * 16) = r;
    } else if (idx < 256 + 1024) {
        // W1 phase-A bf16 B-frags: e = (((tg*4+nt)*2+pair)*4+ql)*16+ml
        const int e = idx - 256;
        const int ml = e & 15, ql = (e >> 4) & 3, pair = (e >> 6) & 1;
        const int nt = (e >> 7) & 3, tg = e >> 9;
        const int colb = nt * 16 + ml;
        const int kbase = tg * 64 + pair * 32 + ql * 8;
        uint4 pk;
        pk.x = pack_bf16_rne(W1[(kbase + 0) * 64 + colb], W1[(kbase + 1) * 64 + colb]);
        pk.y = pack_bf16_rne(W1[(kbase + 2) * 64 + colb], W1[(kbase + 3) * 64 + colb]);
        pk.z = pack_bf16_rne(W1[(kbase + 4) * 64 + colb], W1[(kbase + 5) * 64 + colb]);
        pk.w = pack_bf16_rne(W1[(kbase + 6) * 64 + colb], W1[(kbase + 7) * 64 + colb]);
        *(uint4*)(ws + WS_W1 + e * 16) = pk;
    } else if (idx < 256 + 1024 + 48) {
        // W1 rows 128..133 f16: e = (s*2+half)*4+ql
        const int e = idx - 1280;
        const int ql = e & 3, half = (e >> 2) & 1, s = e >> 3;
        const float* base = W1 + 128 * 64 + s * 64 + half * 32 + ql * 8;
        h8v r;
        #pragma unroll
        for (int k = 0; k < 8; ++k) r[k] = (_Float16)base[k];
        *(h8v*)(ws + WS_W1S + e * 16) = r;
    }
}

// History: R0-R8 static resources exhausted (dur pinned ~89.5us, occupancy
// pinned ~2.25 waves/SIMD regardless of LDS 26-42KB / VGPR 64-104 / grid
// 2048-4096 / block 256-512). R9 phase-A->MFMA: -7% (instruction cuts work).
// R10 f16 main loop: flat (VOP3P FLOP-rate-equal f16/f32). R11 split-block:
// +8us (occupancy still pinned; duplicated phase A is pure overhead).
// Model: time = total VALU instrs / fixed concurrency. R12: delete the
// per-block re-conversion of constant weights via prep_kernel + d_ws
// (~280 instrs/thread -> ~24 b128 loads). Math bit-identical to R10.
__global__ __launch_bounds__(256, 2) void edge_kernel(
    const float* __restrict__ cel,    // (B,S,N,D)
    const float* __restrict__ theta,  // (B,N)
    const float* __restrict__ phi,
    const float* __restrict__ vel,
    const float* __restrict__ rad,
    const float* __restrict__ lon,
    const float* __restrict__ W1,     // (134,64)
    const float* __restrict__ b1,     // (64)
    const float* __restrict__ W2,     // (64,32)
    const float* __restrict__ b2,     // (32)
    const float* __restrict__ W3,     // (32)
    const float* __restrict__ b3,     // (1)
    const float* __restrict__ pw,     // (6)
    const unsigned char* __restrict__ ws,  // pre-packed fragments
    float* __restrict__ out)          // (B,N,N)
{
    __shared__ __align__(16) _Float16 sAiH[NN * LDAH];  // fi@W1[0:64]+b1, f16
    __shared__ __align__(16) _Float16 sBjH[NN * LDAH];  // fj@W1[64:128], f16
    __shared__ float sAdj[1024];
    __shared__ __align__(16) float sScal[NP * 8];       // {td,pd,vd,rr}|{ld,pr,gate,-}
    __shared__ unsigned char sI[NP], sJ[NP];

    const int b = blockIdx.x;
    const int t = threadIdx.x;
    const int ml = t & 15;            // frag row-within-tile / C col
    const int ql = (t >> 4) & 3;      // frag k-quad / C row-quad
    const int wv = t >> 6;            // wave id
    const int kA = ql * 8;            // this lane's ks0 k-base

    // ---- W2 f16 B-fragments: 4 b128 loads from ws (was 64 load+cvt) ----
    const int laneoff = (ql * 16 + ml) * 16;
    const h8v f00h = *(const h8v*)(ws + WS_W2 + 0 * 1024 + laneoff);
    const h8v f01h = *(const h8v*)(ws + WS_W2 + 1 * 1024 + laneoff);
    const h8v f10h = *(const h8v*)(ws + WS_W2 + 2 * 1024 + laneoff);
    const h8v f11h = *(const h8v*)(ws + WS_W2 + 3 * 1024 + laneoff);
    const float b2v0 = b2[ml], b2v1 = b2[16 + ml];
    const float w3v0 = W3[ml], w3v1 = W3[16 + ml];
    const float b3s  = b3[0];

    // ---- staging ----
    if (t < 31) {  // triu pair table
        int off = t * 31 - (t * (t - 1)) / 2;
        for (int j = t + 1; j < 32; ++j) {
            sI[off] = (unsigned char)t;
            sJ[off] = (unsigned char)j;
            ++off;
        }
    }
    for (int idx = t; idx < 1024; idx += 256) sAdj[idx] = 0.0f;
    __syncthreads();   // barrier 1

    // ---- per-pair scalars + gate (f32, unchanged) ----
    for (int p = t; p < NP; p += 256) {
        const int i = sI[p], j = sJ[p];
        const float td = wrap_pi(theta[b * NN + i] - theta[b * NN + j]);
        const float pd = wrap_pi(phi[b * NN + i] - phi[b * NN + j]);
        const float vd = vel[b * NN + i] - vel[b * NN + j];
        const float rr = rad[b * NN + i] * __builtin_amdgcn_rcpf(rad[b * NN + j] + 1e-8f);
        const float ld = wrap_pi(lon[b * NN + i] - lon[b * NN + j]);
        const float pr = __cosf(td) * __cosf(pd);
        const float pf = fabsf(td) * pw[0] + fabsf(pd) * pw[1]
                       + fabsf(vd) * pw[2] + fabsf(rr - 1.0f) * pw[3]
                       + fabsf(ld) * pw[4] + fabsf(pr) * pw[5];
        const int sw = (p >> 2) & 1;   // chunk XOR-swizzle bit
        float4* c0 = (float4*)&sScal[p * 8 + (sw << 2)];
        float4* c1 = (float4*)&sScal[p * 8 + ((sw ^ 1) << 2)];
        *c0 = float4{td, pd, vd, rr};
        *c1 = float4{ld, pr, sigmoid_(pf), 0.0f};
    }

    // ---- phase A on the MATRIX pipe (R9 math): split-bf16 A x bf16 W1
    // (B-frags now 2 b128 loads/nt from ws; was 32 load + 8 pack), b1 in
    // C-init; f16 store to LDS. ----
    {
        const int w4 = __builtin_amdgcn_readfirstlane(t >> 6);
        const int tg = w4 >> 1;
        const int mt = w4 & 1;
        const float* fbase = cel + ((size_t)b * SS + (SS - 1)) * (NN * DD);
        const float* Arow = fbase + (mt * 16 + ml) * 64;
        const float4 e0 = *(const float4*)(Arow + kA);
        const float4 e1 = *(const float4*)(Arow + kA + 4);
        const float4 e2 = *(const float4*)(Arow + 32 + kA);
        const float4 e3 = *(const float4*)(Arow + 36 + kA);
        FragU Ah0, Al0, Ah1, Al1;
        Ah0.u.x = pack_bf16_rne(e0.x, e0.y);
        Ah0.u.y = pack_bf16_rne(e0.z, e0.w);
        Ah0.u.z = pack_bf16_rne(e1.x, e1.y);
        Ah0.u.w = pack_bf16_rne(e1.z, e1.w);
        Al0.u.x = res_pack(Ah0.u.x, e0.x, e0.y);
        Al0.u.y = res_pack(Ah0.u.y, e0.z, e0.w);
        Al0.u.z = res_pack(Ah0.u.z, e1.x, e1.y);
        Al0.u.w = res_pack(Ah0.u.w, e1.z, e1.w);
        Ah1.u.x = pack_bf16_rne(e2.x, e2.y);
        Ah1.u.y = pack_bf16_rne(e2.z, e2.w);
        Ah1.u.z = pack_bf16_rne(e3.x, e3.y);
        Ah1.u.w = pack_bf16_rne(e3.z, e3.w);
        Al1.u.x = res_pack(Ah1.u.x, e2.x, e2.y);
        Al1.u.y = res_pack(Ah1.u.y, e2.z, e2.w);
        Al1.u.z = res_pack(Ah1.u.z, e3.x, e3.y);
        Al1.u.w = res_pack(Ah1.u.w, e3.z, e3.w);

        const unsigned char* wB = ws + WS_W1 + (tg * 512 + ql * 16 + ml) * 16;
        _Float16* dstS = tg ? sBjH : sAiH;
        #pragma clang loop unroll(disable)   // serial nt: cap VGPR liveness
        for (int nt = 0; nt < 4; ++nt) {
            FragU B0, B1;
            B0.u = *(const uint4*)(wB + (nt * 128 + 0) * 16);
            B1.u = *(const uint4*)(wB + (nt * 128 + 64) * 16);
            const int colb = nt * 16 + ml;
            const float cinit = tg ? 0.0f : b1[colb];
            v4f acc = {cinit, cinit, cinit, cinit};
            acc = __builtin_amdgcn_mfma_f32_16x16x32_bf16(Ah0.s, B0.s, acc, 0, 0, 0);
            acc = __builtin_amdgcn_mfma_f32_16x16x32_bf16(Al0.s, B0.s, acc, 0, 0, 0);
            acc = __builtin_amdgcn_mfma_f32_16x16x32_bf16(Ah1.s, B1.s, acc, 0, 0, 0);
            acc = __builtin_amdgcn_mfma_f32_16x16x32_bf16(Al1.s, B1.s, acc, 0, 0, 0);
            dstS[(mt * 16 + ql * 4 + 0) * LDAH + colb] = (_Float16)acc[0];
            dstS[(mt * 16 + ql * 4 + 1) * LDAH + colb] = (_Float16)acc[1];
            dstS[(mt * 16 + ql * 4 + 2) * LDAH + colb] = (_Float16)acc[2];
            dstS[(mt * 16 + ql * 4 + 3) * LDAH + colb] = (_Float16)acc[3];
        }
    }
    __syncthreads();   // barrier 2

    // ---- W1s hoist: 12 b128 loads from ws (was 24 b128 + 96 cvt) ----
    h8v w1fh[6][2];
    #pragma unroll
    for (int s = 0; s < 6; ++s) {
        w1fh[s][0] = *(const h8v*)(ws + WS_W1S + ((s * 2 + 0) * 4 + ql) * 16);
        w1fh[s][1] = *(const h8v*)(ws + WS_W1S + ((s * 2 + 1) * 4 + ql) * 16);
    }

    // ---- main loop: one 16-pair m-tile per wave-round, ZERO barriers ----
    #pragma clang loop unroll(disable)
    for (int r = 0; r < 8; ++r) {
        const int mtl = r * 4 + wv;
        if (mtl >= 31) break;                    // wave-uniform
        const int p = mtl * 16 + ml;
        const int i = sI[p], j = sJ[p];
        const int sw = (p >> 2) & 1;
        Q2 S0, S1;
        S0.q = *(const float4*)&sScal[p * 8 + (sw << 2)];        // td,pd,vd,rr
        S1.q = *(const float4*)&sScal[p * 8 + ((sw ^ 1) << 2)];  // ld,pr,gate,-
        const _Float16 sch[6] = {
            (_Float16)S0.q.x, (_Float16)S0.q.y, (_Float16)S0.q.z,
            (_Float16)fminf(S0.q.w, 30000.0f),   // f16-inf guard on rr
            (_Float16)S1.q.x, (_Float16)S1.q.y};
        const _Float16* ArH = &sAiH[i * LDAH];
        const _Float16* BrH = &sBjH[j * LDAH];

        // ks0 half: cols kA..kA+7
        h8v v0;
        {
            const h8v P = *(const h8v*)(ArH + kA);
            const h8v Q = *(const h8v*)(BrH + kA);
            h8v v = P + Q;
            #pragma unroll
            for (int s = 0; s < 6; ++s)
                v = __builtin_elementwise_fma(splat8hh(sch[s]), w1fh[s][0], v);
            v0 = gelu8h(v);
        }
        // ks1 half: cols 32+kA..+7
        h8v v1;
        {
            const h8v P = *(const h8v*)(ArH + 32 + kA);
            const h8v Q = *(const h8v*)(BrH + 32 + kA);
            h8v y = P + Q;
            #pragma unroll
            for (int s = 0; s < 6; ++s)
                y = __builtin_elementwise_fma(splat8hh(sch[s]), w1fh[s][1], y);
            v1 = gelu8h(y);
        }

        // h2 = h1 @ W2 on the matrix pipe (f16 operands)
        v4f acc0 = {b2v0, b2v0, b2v0, b2v0};
        v4f acc1 = {b2v1, b2v1, b2v1, b2v1};
        acc0 = __builtin_amdgcn_mfma_f32_16x16x32_f16(v0, f00h, acc0, 0, 0, 0);
        acc0 = __builtin_amdgcn_mfma_f32_16x16x32_f16(v1, f01h, acc0, 0, 0, 0);
        acc1 = __builtin_amdgcn_mfma_f32_16x16x32_f16(v0, f10h, acc1, 0, 0, 0);
        acc1 = __builtin_amdgcn_mfma_f32_16x16x32_f16(v1, f11h, acc1, 0, 0, 0);

        // epilogue (f32): pk gelu + W3 dot + DPP row reduce
        float cres[4];
        #pragma unroll
        for (int rr2 = 0; rr2 < 4; ++rr2) {
            const f2 g = gelu2(f2m(acc0[rr2], acc1[rr2]));
            cres[rr2] = row_reduce16(fmaf(g.y, w3v1, g.x * w3v0));
        }
        const int rsel = ml & 3;
        const float cs = (rsel & 2) ? ((rsel & 1) ? cres[3] : cres[2])
                                    : ((rsel & 1) ? cres[1] : cres[0]);
        const int pe = mtl * 16 + ql * 4 + rsel;
        const int swe = (pe >> 2) & 1;
        const float gate = sScal[pe * 8 + ((swe ^ 1) << 2) + 2];
        const float fe = sigmoid_(cs + b3s) * gate;
        if (ml < 4) {
            const int pi = sI[pe], pj = sJ[pe];
            sAdj[pi * 32 + pj] = fe;
            sAdj[pj * 32 + pi] = fe;
        }
    }
    __syncthreads();   // barrier 3

    // ---- coalesced tile writeback ----
    float* dst = out + (size_t)b * 1024;
    for (int idx = t; idx < 1024; idx += 256) dst[idx] = sAdj[idx];
}

extern "C" void kernel_launch(void* const* d_in, const int* in_sizes, int n_in,
                              void* d_out, int out_size, void* d_ws, size_t ws_size,
                              hipStream_t stream) {
    const float* cel   = (const float*)d_in[0];
    const float* theta = (const float*)d_in[1];
    const float* phi   = (const float*)d_in[2];
    const float* vel   = (const float*)d_in[3];
    const float* rad   = (const float*)d_in[4];
    const float* lon   = (const float*)d_in[5];
    const float* W1    = (const float*)d_in[6];
    const float* b1    = (const float*)d_in[7];
    const float* W2    = (const float*)d_in[8];
    const float* b2    = (const float*)d_in[9];
    const float* W3    = (const float*)d_in[10];
    const float* b3    = (const float*)d_in[11];
    const float* pw    = (const float*)d_in[12];
    float* out = (float*)d_out;
    unsigned char* ws = (unsigned char*)d_ws;

    const int B = in_sizes[1] / NN;  // theta is (B,N)
    // prep: 1328 entries / 256 threads -> 6 blocks; runs before edge on the
    // same stream (captured in the graph, deterministic every replay).
    prep_kernel<<<6, 256, 0, stream>>>(W1, W2, ws);
    edge_kernel<<<B, 256, 0, stream>>>(cel, theta, phi, vel, rad, lon,
                                       W1, b1, W2, b2, W3, b3, pw, ws, out);
}